// Round 4
// baseline (690.734 us; speedup 1.0000x reference)
//
#include <hip/hip_runtime.h>

#define D_MODEL 1024
#define D_FF    8192
#define N_ELEM  64
#define D1      128
#define BATCH   2048
#define B_T     8      // batch rows per block (main kernel)
#define NJT     8      // j tiles (== XCD count)
#define JT      16     // j per tile
#define NGRP    (BATCH / B_T)   // 256 b0 groups

typedef unsigned short u16;
typedef unsigned int   u32;
typedef _Float16 h2    __attribute__((ext_vector_type(2)));
typedef float    f32x4 __attribute__((ext_vector_type(4)));
typedef u32      u32x2 __attribute__((ext_vector_type(2)));
typedef u32      u32x4 __attribute__((ext_vector_type(4)));

__device__ __forceinline__ h2 as_h2(u32 u) { union { u32 i; h2 h; } c; c.i = u; return c.h; }
__device__ __forceinline__ u32 pkh(float a, float b) {
    union { h2 h; u32 u; } c; c.h.x = (_Float16)a; c.h.y = (_Float16)b; return c.u;
}
__device__ __forceinline__ u16 f2h(float f) {
    union { _Float16 h; u16 u; } c; c.h = (_Float16)f; return c.u;
}
__device__ __forceinline__ f32x4 ntload4(const float* p) {
    return __builtin_nontemporal_load((const f32x4*)p);
}
// 2-way f16 dot with f32 accumulate: v_dot2_f32_f16 (2 MAC/inst).
__device__ __forceinline__ float dot2(u32 a, u32 b, float c) {
#if __has_builtin(__builtin_amdgcn_fdot2)
    return __builtin_amdgcn_fdot2(as_h2(a), as_h2(b), c, false);
#else
    const h2 ha = as_h2(a), hb = as_h2(b);
    c = fmaf((float)ha.x, (float)hb.x, c);
    return fmaf((float)ha.y, (float)hb.y, c);
#endif
}
__device__ __forceinline__ float dot8(uint4 w, uint4 q, float c) {
    c = dot2(w.x, q.x, c);
    c = dot2(w.y, q.y, c);
    c = dot2(w.z, q.z, c);
    c = dot2(w.w, q.w, c);
    return c;
}

// ---------------------------------------------------------------------------
// Wave-64 sum reduction. DPP path: 6 VALU-pipe levels (row_shr 1/2/4/8,
// row_bcast 15/31), total in lane 63. Replaces the 6-level ds_bpermute
// (__shfl_down) chain: ~40cy DS latency/level -> ~8cy VALU latency/level.
// ---------------------------------------------------------------------------
#if __has_builtin(__builtin_amdgcn_update_dpp)
#define WRITER_LANE 63
#define DPP_ADD(x, ctrl)                                                      \
    x += __builtin_bit_cast(float, __builtin_amdgcn_update_dpp(               \
        0, __builtin_bit_cast(int, x), ctrl, 0xf, 0xf, true))
__device__ __forceinline__ float wave_sum64(float x) {
    DPP_ADD(x, 0x111);   // row_shr:1
    DPP_ADD(x, 0x112);   // row_shr:2
    DPP_ADD(x, 0x114);   // row_shr:4
    DPP_ADD(x, 0x118);   // row_shr:8  -> lane 15+16k holds row-k sum
    DPP_ADD(x, 0x142);   // row_bcast:15 -> lane31 = r0+r1, lane63 = r2+r3
    DPP_ADD(x, 0x143);   // row_bcast:31 -> lane63 = total
    return x;
}
#else
#define WRITER_LANE 0
__device__ __forceinline__ float wave_sum64(float x) {
#pragma unroll
    for (int off = 32; off; off >>= 1) x += __shfl_down(x, off);
    return x;
}
#endif

// ---------------------------------------------------------------------------
// Fused prep: blocks [0,2048) transpose+cast w1 -> w1h [j*64+e][d] f16;
// blocks [2048,6144) cast w2 -> f16. (Verified rounds 1-3.)
// ---------------------------------------------------------------------------
#define TW1_BLOCKS ((D_FF / 64) * (D_MODEL / 64))   // 2048
__global__ __launch_bounds__(256) void prep_weights(const float* __restrict__ w1,
                                                    u16* __restrict__ w1h,
                                                    const float* __restrict__ w2,
                                                    u16* __restrict__ w2h) {
    __shared__ float tile[64][65];
    if (blockIdx.x < TW1_BLOCKS) {
        const int c0 = (blockIdx.x & (D_FF / 64 - 1)) * 64;
        const int d0 = (blockIdx.x >> 7) * 64;          // D_FF/64 == 128
        const int tx = threadIdx.x & 15;
        const int ty = threadIdx.x >> 4;
#pragma unroll
        for (int r = 0; r < 4; ++r) {
            const int row = ty * 4 + r;
            const float4 v = *(const float4*)(w1 + (size_t)(d0 + row) * D_FF + c0 + tx * 4);
            tile[row][tx * 4 + 0] = v.x;
            tile[row][tx * 4 + 1] = v.y;
            tile[row][tx * 4 + 2] = v.z;
            tile[row][tx * 4 + 3] = v.w;
        }
        __syncthreads();
#pragma unroll
        for (int r = 0; r < 4; ++r) {
            const int c = ty * 4 + r;
            ushort4 o;
            o.x = f2h(tile[tx * 4 + 0][c]);
            o.y = f2h(tile[tx * 4 + 1][c]);
            o.z = f2h(tile[tx * 4 + 2][c]);
            o.w = f2h(tile[tx * 4 + 3][c]);
            *(ushort4*)(w1h + (size_t)(c0 + c) * D_MODEL + d0 + tx * 4) = o;
        }
    } else {
        const size_t i = ((size_t)(blockIdx.x - TW1_BLOCKS) * 256 + threadIdx.x) * 8;
        const float4 a = *(const float4*)(w2 + i);
        const float4 b = *(const float4*)(w2 + i + 4);
        ushort4 oa, ob;
        oa.x = f2h(a.x); oa.y = f2h(a.y); oa.z = f2h(a.z); oa.w = f2h(a.w);
        ob.x = f2h(b.x); ob.y = f2h(b.y); ob.z = f2h(b.z); ob.w = f2h(b.w);
        *(ushort4*)(w2h + i)     = oa;
        *(ushort4*)(w2h + i + 4) = ob;
    }
}

// ---------------------------------------------------------------------------
// Main. r3 skeleton + round-4 changes:
//   phase 1: DPP wave reduction (VALU pipe) instead of __shfl_down (DS pipe).
//     r0-r3 proved the kernel is pinned at 62us across load-ILP/branch/dot
//     variants with VALUBusy only ~40% -> the serial 6-level ds_bpermute
//     chains (~2000cy/wave) are the prime critical-path suspect.
//   phase 2: paired even/odd jj accumulator streams (independent fmaf
//     chains, 2 loads per step), branchless, 8 dims/thread.
//   fused cross-jt reduction: last block per b0 group (device-scope atomic
//     counter, canonical threadfence/syncthreads/atomicAdd pattern) sums the
//     8 partials, adds b2, writes f32 out + mask echo. Removes the
//     reduce_partials launch. Counter zeroed via hipMemsetAsync per call.
// ---------------------------------------------------------------------------
__global__ __launch_bounds__(256) void sparse_ff_jt(const int* __restrict__ mask,
                                                    const float* __restrict__ x,
                                                    const u16* __restrict__ w1h_,
                                                    const u16* __restrict__ w2h_,
                                                    u16* part,
                                                    int* cnt,
                                                    const float* __restrict__ b2,
                                                    float* __restrict__ out) {
    const _Float16* w1h = (const _Float16*)w1h_;
    const _Float16* w2h = (const _Float16*)w2h_;
    __shared__ u16   x_lds[B_T][D_MODEL];   // f16, 16 KB
    __shared__ float r_lds[B_T][JT];
    __shared__ int   m_lds[B_T][JT];
    __shared__ int   last_flag;

    const int jt = blockIdx.x & (NJT - 1);          // XCD-affine j tile
    const int b0 = (blockIdx.x >> 3) * B_T;
    const int t = threadIdx.x;
    const int wave = t >> 6;
    const int lane = t & 63;

    // stage x rows (f32 nt coalesced -> f16 LDS) + mask row, one barrier
#pragma unroll
    for (int r = 0; r < B_T; ++r) {
        const f32x4 v = ntload4(x + (size_t)(b0 + r) * D_MODEL + t * 4);
        u32x2 o; o.x = pkh(v.x, v.y); o.y = pkh(v.z, v.w);
        *(u32x2*)&x_lds[r][t * 4] = o;
    }
    if (t < B_T * JT) {
        m_lds[t >> 4][t & 15] = mask[(b0 + (t >> 4)) * D1 + jt * JT + (t & 15)];
    }
    __syncthreads();

    // ---- phase 1: wave handles 2 batch rows x 16 j, 4 j per step ----
#pragma unroll
    for (int rep = 0; rep < 2; ++rep) {
        const int bi = wave * 2 + rep;
        const uint4 xA = *(const uint4*)&x_lds[bi][lane * 8];
        const uint4 xB = *(const uint4*)&x_lds[bi][512 + lane * 8];

#pragma unroll
        for (int jj = 0; jj < JT; jj += 4) {
            const int j0 = jt * JT + jj;
            const _Float16* c0 = w1h + (size_t)(((j0 + 0) << 6) + m_lds[bi][jj + 0]) * D_MODEL + lane * 8;
            const _Float16* c1 = w1h + (size_t)(((j0 + 1) << 6) + m_lds[bi][jj + 1]) * D_MODEL + lane * 8;
            const _Float16* c2 = w1h + (size_t)(((j0 + 2) << 6) + m_lds[bi][jj + 2]) * D_MODEL + lane * 8;
            const _Float16* c3 = w1h + (size_t)(((j0 + 3) << 6) + m_lds[bi][jj + 3]) * D_MODEL + lane * 8;
            const uint4 a0 = *(const uint4*)c0;
            const uint4 a1 = *(const uint4*)c1;
            const uint4 a2 = *(const uint4*)c2;
            const uint4 a3 = *(const uint4*)c3;
            const uint4 e0 = *(const uint4*)(c0 + 512);
            const uint4 e1 = *(const uint4*)(c1 + 512);
            const uint4 e2 = *(const uint4*)(c2 + 512);
            const uint4 e3 = *(const uint4*)(c3 + 512);

            float s0 = dot8(a0, xA, 0.f); s0 = dot8(e0, xB, s0);
            float s1 = dot8(a1, xA, 0.f); s1 = dot8(e1, xB, s1);
            float s2 = dot8(a2, xA, 0.f); s2 = dot8(e2, xB, s2);
            float s3 = dot8(a3, xA, 0.f); s3 = dot8(e3, xB, s3);

            s0 = wave_sum64(s0);
            s1 = wave_sum64(s1);
            s2 = wave_sum64(s2);
            s3 = wave_sum64(s3);
            if (lane == WRITER_LANE) {
                r_lds[bi][jj + 0] = fmaxf(s0, 0.f);
                r_lds[bi][jj + 1] = fmaxf(s1, 0.f);
                r_lds[bi][jj + 2] = fmaxf(s2, 0.f);
                r_lds[bi][jj + 3] = fmaxf(s3, 0.f);
            }
        }
    }
    __syncthreads();

    // ---- phase 2: branchless, wave-pair split, 8 dims/thread, paired jj ----
    const int halfsel = t >> 7;            // waves 0-1 -> bi even, 2-3 -> bi odd
    const int d0q = (t & 127) * 8;
#pragma unroll
    for (int p = 0; p < 4; ++p) {
        const int bi = p * 2 + halfsel;
        float e0 = 0.f, e1 = 0.f, e2 = 0.f, e3 = 0.f;
        float e4 = 0.f, e5 = 0.f, e6 = 0.f, e7 = 0.f;
        float o0 = 0.f, o1 = 0.f, o2 = 0.f, o3 = 0.f;
        float o4 = 0.f, o5 = 0.f, o6 = 0.f, o7 = 0.f;
#pragma unroll
        for (int jj = 0; jj < JT; jj += 2) {
            const float rE = r_lds[bi][jj];
            const float rO = r_lds[bi][jj + 1];
            const _Float16* rowE = w2h
                + (size_t)(m_lds[bi][jj] * D1 + jt * JT + jj) * D_MODEL + d0q;
            const _Float16* rowO = w2h
                + (size_t)(m_lds[bi][jj + 1] * D1 + jt * JT + jj + 1) * D_MODEL + d0q;
            const uint4 vE = *(const uint4*)rowE;
            const uint4 vO = *(const uint4*)rowO;
            {
                const h2 q0 = as_h2(vE.x), q1 = as_h2(vE.y);
                const h2 q2 = as_h2(vE.z), q3 = as_h2(vE.w);
                e0 = fmaf(rE, (float)q0.x, e0); e1 = fmaf(rE, (float)q0.y, e1);
                e2 = fmaf(rE, (float)q1.x, e2); e3 = fmaf(rE, (float)q1.y, e3);
                e4 = fmaf(rE, (float)q2.x, e4); e5 = fmaf(rE, (float)q2.y, e5);
                e6 = fmaf(rE, (float)q3.x, e6); e7 = fmaf(rE, (float)q3.y, e7);
            }
            {
                const h2 q0 = as_h2(vO.x), q1 = as_h2(vO.y);
                const h2 q2 = as_h2(vO.z), q3 = as_h2(vO.w);
                o0 = fmaf(rO, (float)q0.x, o0); o1 = fmaf(rO, (float)q0.y, o1);
                o2 = fmaf(rO, (float)q1.x, o2); o3 = fmaf(rO, (float)q1.y, o3);
                o4 = fmaf(rO, (float)q2.x, o4); o5 = fmaf(rO, (float)q2.y, o5);
                o6 = fmaf(rO, (float)q3.x, o6); o7 = fmaf(rO, (float)q3.y, o7);
            }
        }
        u32x4 o;
        o.x = pkh(e0 + o0, e1 + o1); o.y = pkh(e2 + o2, e3 + o3);
        o.z = pkh(e4 + o4, e5 + o5); o.w = pkh(e6 + o6, e7 + o7);
        u16* pp = part + ((size_t)jt * BATCH + (b0 + bi)) * D_MODEL + d0q;
        __builtin_nontemporal_store(o, (u32x4*)pp);
    }

    // ---- fused cross-jt reduction: last block of this b0 group does it ----
    __threadfence();                                   // release partials
    __syncthreads();
    if (t == 0)
        last_flag = (atomicAdd(&cnt[blockIdx.x >> 3], 1) == NJT - 1);
    __syncthreads();
    if (!last_flag) return;
    __threadfence();                                   // acquire partials

    if (t < D1) {
#pragma unroll
        for (int bi = 0; bi < B_T; ++bi)
            out[(size_t)(b0 + bi) * D1 + t] = (float)mask[(b0 + bi) * D1 + t];
    }
    const int d0 = t * 4;
    const float4 bv = *(const float4*)(b2 + d0);
#pragma unroll
    for (int bi = 0; bi < B_T; ++bi) {
        float a0 = bv.x, a1 = bv.y, a2 = bv.z, a3 = bv.w;
#pragma unroll
        for (int q = 0; q < NJT; ++q) {
            const uint2 v = *(const uint2*)(part + ((size_t)q * BATCH + (b0 + bi)) * D_MODEL + d0);
            const h2 p0 = as_h2(v.x), p1 = as_h2(v.y);
            a0 += (float)p0.x; a1 += (float)p0.y;
            a2 += (float)p1.x; a3 += (float)p1.y;
        }
        *(float4*)(out + (size_t)BATCH * D1 + (size_t)(b0 + bi) * D_MODEL + d0) =
            make_float4(a0, a1, a2, a3);
    }
}

// ---------------------------------------------------------------------------
// Fallback (tiny ws): fp32 path, raw strided w1 gather
// ---------------------------------------------------------------------------
__global__ __launch_bounds__(256) void sparse_ff_f32_raw(const int* __restrict__ mask,
                                                         const float* __restrict__ x,
                                                         const float* __restrict__ w1,
                                                         const float* __restrict__ w2,
                                                         const float* __restrict__ b2,
                                                         float* __restrict__ out) {
    __shared__ float x_lds[D_MODEL];
    __shared__ float relu_lds[D1];
    __shared__ int   m_lds[D1];
    const int b = blockIdx.x, t = threadIdx.x;
    const int wave = t >> 6, lane = t & 63;
    *(float4*)&x_lds[t * 4] = *(const float4*)(x + (size_t)b * D_MODEL + t * 4);
    if (t < D1) {
        const int mv = mask[b * D1 + t];
        m_lds[t] = mv;
        out[(size_t)b * D1 + t] = (float)mv;
    }
    __syncthreads();
    for (int jj = 0; jj < 32; ++jj) {
        const int j = wave * 32 + jj;
        const int m = m_lds[j];
        float acc = 0.f;
#pragma unroll
        for (int c = 0; c < 16; ++c) {
            const int d = c * 64 + lane;
            acc = fmaf(w1[(size_t)d * D_FF + j * N_ELEM + m], x_lds[d], acc);
        }
#pragma unroll
        for (int off = 32; off; off >>= 1) acc += __shfl_down(acc, off);
        if (lane == 0) relu_lds[j] = fmaxf(acc, 0.f);
    }
    __syncthreads();
    const int dm0 = t * 4;
    const float4 bv = *(const float4*)(b2 + dm0);
    float a0 = bv.x, a1 = bv.y, a2 = bv.z, a3 = bv.w;
    for (int j = 0; j < D1; ++j) {
        const float r = relu_lds[j];
        if (r > 0.f) {
            const float4 wv = *(const float4*)(w2 + (size_t)(m_lds[j] * D1 + j) * D_MODEL + dm0);
            a0 = fmaf(r, wv.x, a0); a1 = fmaf(r, wv.y, a1);
            a2 = fmaf(r, wv.z, a2); a3 = fmaf(r, wv.w, a3);
        }
    }
    *(float4*)(out + (size_t)BATCH * D1 + (size_t)b * D_MODEL + dm0) =
        make_float4(a0, a1, a2, a3);
}

extern "C" void kernel_launch(void* const* d_in, const int* in_sizes, int n_in,
                              void* d_out, int out_size, void* d_ws, size_t ws_size,
                              hipStream_t stream) {
    const int*   mask = (const int*)d_in[0];
    const float* x    = (const float*)d_in[1];
    const float* w1   = (const float*)d_in[2];
    const float* w2   = (const float*)d_in[3];
    const float* b2   = (const float*)d_in[4];
    float* out = (float*)d_out;

    const size_t w1h_bytes  = (size_t)D_FF * D_MODEL * sizeof(u16);          // 16 MiB
    const size_t w2h_bytes  = (size_t)D_FF * D_MODEL * sizeof(u16);          // 16 MiB
    const size_t part_bytes = (size_t)NJT * BATCH * D_MODEL * sizeof(u16);   // 32 MiB
    const size_t cnt_bytes  = (size_t)NGRP * sizeof(int);                    // 1 KiB

    if (ws_size >= w1h_bytes + w2h_bytes + part_bytes + cnt_bytes) {
        u16* w1h  = (u16*)d_ws;
        u16* w2h  = (u16*)((char*)d_ws + w1h_bytes);
        u16* part = (u16*)((char*)d_ws + w1h_bytes + w2h_bytes);
        int* cnt  = (int*)((char*)d_ws + w1h_bytes + w2h_bytes + part_bytes);
        hipMemsetAsync(cnt, 0, cnt_bytes, stream);
        const int cast_blocks = (D_FF * D_MODEL / 8) / 256;                  // 4096
        prep_weights<<<TW1_BLOCKS + cast_blocks, 256, 0, stream>>>(w1, w1h, w2, w2h);
        sparse_ff_jt<<<(BATCH / B_T) * NJT, 256, 0, stream>>>(mask, x, w1h, w2h,
                                                              part, cnt, b2, out);
    } else {
        sparse_ff_f32_raw<<<BATCH, 256, 0, stream>>>(mask, x, w1, w2, b2, out);
    }
}

// Round 5
// 193.841 us; speedup vs baseline: 3.5634x; 3.5634x over previous
//
#include <hip/hip_runtime.h>

#define D_MODEL 1024
#define D_FF    8192
#define N_ELEM  64
#define D1      128
#define BATCH   2048
#define B_T     8      // batch rows per block (main kernel)
#define NJT     8      // j tiles (== XCD count)
#define JT      16     // j per tile

typedef unsigned short u16;
typedef unsigned int   u32;
typedef _Float16 h2    __attribute__((ext_vector_type(2)));
typedef float    f32x4 __attribute__((ext_vector_type(4)));
typedef u32      u32x2 __attribute__((ext_vector_type(2)));
typedef u32      u32x4 __attribute__((ext_vector_type(4)));

__device__ __forceinline__ h2 as_h2(u32 u) { union { u32 i; h2 h; } c; c.i = u; return c.h; }
__device__ __forceinline__ u32 pkh(float a, float b) {
    union { h2 h; u32 u; } c; c.h.x = (_Float16)a; c.h.y = (_Float16)b; return c.u;
}
__device__ __forceinline__ u16 f2h(float f) {
    union { _Float16 h; u16 u; } c; c.h = (_Float16)f; return c.u;
}
__device__ __forceinline__ f32x4 ntload4(const float* p) {
    return __builtin_nontemporal_load((const f32x4*)p);
}
// 2-way f16 dot with f32 accumulate: v_dot2_f32_f16 (2 MAC/inst).
__device__ __forceinline__ float dot2(u32 a, u32 b, float c) {
#if __has_builtin(__builtin_amdgcn_fdot2)
    return __builtin_amdgcn_fdot2(as_h2(a), as_h2(b), c, false);
#else
    const h2 ha = as_h2(a), hb = as_h2(b);
    c = fmaf((float)ha.x, (float)hb.x, c);
    return fmaf((float)ha.y, (float)hb.y, c);
#endif
}
__device__ __forceinline__ float dot8(uint4 w, uint4 q, float c) {
    c = dot2(w.x, q.x, c);
    c = dot2(w.y, q.y, c);
    c = dot2(w.z, q.z, c);
    c = dot2(w.w, q.w, c);
    return c;
}

// ---------------------------------------------------------------------------
// Wave-64 sum reduction on the VALU pipe via DPP (functionally verified in
// round 4: harness passed with this path). Total lands in lane 63.
// ---------------------------------------------------------------------------
#if __has_builtin(__builtin_amdgcn_update_dpp)
#define WRITER_LANE 63
#define DPP_ADD(x, ctrl)                                                      \
    x += __builtin_bit_cast(float, __builtin_amdgcn_update_dpp(               \
        0, __builtin_bit_cast(int, x), ctrl, 0xf, 0xf, true))
__device__ __forceinline__ float wave_sum64(float x) {
    DPP_ADD(x, 0x111);   // row_shr:1
    DPP_ADD(x, 0x112);   // row_shr:2
    DPP_ADD(x, 0x114);   // row_shr:4
    DPP_ADD(x, 0x118);   // row_shr:8  -> lane 15+16k holds row-k sum
    DPP_ADD(x, 0x142);   // row_bcast:15 -> lane31 = r0+r1, lane63 = r2+r3
    DPP_ADD(x, 0x143);   // row_bcast:31 -> lane63 = total
    return x;
}
#else
#define WRITER_LANE 0
__device__ __forceinline__ float wave_sum64(float x) {
#pragma unroll
    for (int off = 32; off; off >>= 1) x += __shfl_down(x, off);
    return x;
}
#endif
// broadcast lane `srclane` to all lanes as a wave-uniform (SGPR) value
__device__ __forceinline__ float bcast_lane(float x, int srclane) {
#if __has_builtin(__builtin_amdgcn_readlane)
    return __builtin_bit_cast(float,
        __builtin_amdgcn_readlane(__builtin_bit_cast(int, x), srclane));
#else
    return __shfl(x, srclane);
#endif
}

// ---------------------------------------------------------------------------
// Fused prep: blocks [0,2048) transpose+cast w1 -> w1h [j*64+e][d] f16;
// blocks [2048,6144) cast w2 -> f16. (Verified rounds 1-4.)
// ---------------------------------------------------------------------------
#define TW1_BLOCKS ((D_FF / 64) * (D_MODEL / 64))   // 2048
__global__ __launch_bounds__(256) void prep_weights(const float* __restrict__ w1,
                                                    u16* __restrict__ w1h,
                                                    const float* __restrict__ w2,
                                                    u16* __restrict__ w2h) {
    __shared__ float tile[64][65];
    if (blockIdx.x < TW1_BLOCKS) {
        const int c0 = (blockIdx.x & (D_FF / 64 - 1)) * 64;
        const int d0 = (blockIdx.x >> 7) * 64;          // D_FF/64 == 128
        const int tx = threadIdx.x & 15;
        const int ty = threadIdx.x >> 4;
#pragma unroll
        for (int r = 0; r < 4; ++r) {
            const int row = ty * 4 + r;
            const float4 v = *(const float4*)(w1 + (size_t)(d0 + row) * D_FF + c0 + tx * 4);
            tile[row][tx * 4 + 0] = v.x;
            tile[row][tx * 4 + 1] = v.y;
            tile[row][tx * 4 + 2] = v.z;
            tile[row][tx * 4 + 3] = v.w;
        }
        __syncthreads();
#pragma unroll
        for (int r = 0; r < 4; ++r) {
            const int c = ty * 4 + r;
            ushort4 o;
            o.x = f2h(tile[tx * 4 + 0][c]);
            o.y = f2h(tile[tx * 4 + 1][c]);
            o.z = f2h(tile[tx * 4 + 2][c]);
            o.w = f2h(tile[tx * 4 + 3][c]);
            *(ushort4*)(w1h + (size_t)(c0 + c) * D_MODEL + d0 + tx * 4) = o;
        }
    } else {
        const size_t i = ((size_t)(blockIdx.x - TW1_BLOCKS) * 256 + threadIdx.x) * 8;
        const float4 a = *(const float4*)(w2 + i);
        const float4 b = *(const float4*)(w2 + i + 4);
        ushort4 oa, ob;
        oa.x = f2h(a.x); oa.y = f2h(a.y); oa.z = f2h(a.z); oa.w = f2h(a.w);
        ob.x = f2h(b.x); ob.y = f2h(b.y); ob.z = f2h(b.z); ob.w = f2h(b.w);
        *(ushort4*)(w2h + i)     = oa;
        *(ushort4*)(w2h + i + 4) = ob;
    }
}

// ---------------------------------------------------------------------------
// Main, round 5: wave-owned rows, ONE barrier total. r4's cross-XCD fused
// reduction (threadfence = per-block L2 writeback, 62->700us) reverted.
//   - Each wave fully owns 2 batch rows: dot (4-way j ILP, dot2) ->
//     DPP wave reduce (VALU pipe) -> v_readlane(63) puts r_j in an SGPR ->
//     relu -> phase-2 accumulate with scalar r. No r_lds, no 2nd barrier:
//     waves free-run; phase-2 addresses depend only on m so loads can
//     overlap the reduce chains.
//   - Phase 2 per lane: 16 contiguous dims, 2x16B loads + 2x16B nt stores
//     per row (coalesced 2KB/wave).
// ---------------------------------------------------------------------------
__global__ __launch_bounds__(256) void sparse_ff_jt(const int* __restrict__ mask,
                                                    const float* __restrict__ x,
                                                    const u16* __restrict__ w1h_,
                                                    const u16* __restrict__ w2h_,
                                                    u16* __restrict__ part) {
    const _Float16* w1h = (const _Float16*)w1h_;
    const _Float16* w2h = (const _Float16*)w2h_;
    __shared__ u16 x_lds[B_T][D_MODEL];   // f16, 16 KB
    __shared__ int m_lds[B_T][JT];

    const int jt = blockIdx.x & (NJT - 1);          // XCD-affine j tile
    const int b0 = (blockIdx.x >> 3) * B_T;
    const int t = threadIdx.x;
    const int wave = t >> 6;
    const int lane = t & 63;

    // stage x rows (f32 nt coalesced -> f16 LDS) + mask rows, one barrier
#pragma unroll
    for (int r = 0; r < B_T; ++r) {
        const f32x4 v = ntload4(x + (size_t)(b0 + r) * D_MODEL + t * 4);
        u32x2 o; o.x = pkh(v.x, v.y); o.y = pkh(v.z, v.w);
        *(u32x2*)&x_lds[r][t * 4] = o;
    }
    if (t < B_T * JT) {
        m_lds[t >> 4][t & 15] = mask[(b0 + (t >> 4)) * D1 + jt * JT + (t & 15)];
    }
    __syncthreads();

    // ---- each wave owns rows wave*2 and wave*2+1, end-to-end ----
#pragma unroll
    for (int rep = 0; rep < 2; ++rep) {
        const int bi = wave * 2 + rep;
        const uint4 xA = *(const uint4*)&x_lds[bi][lane * 8];        // dims lane*8..+8
        const uint4 xB = *(const uint4*)&x_lds[bi][512 + lane * 8];  // dims 512+..

        int   mj[JT];   // gathered expert ids (unrolled-static indexing only)
        float rj[JT];   // relu'd mids, wave-uniform (SGPR after readlane)

        // phase 1: 4 j per step, 4 independent dot + reduce chains
#pragma unroll
        for (int jj = 0; jj < JT; jj += 4) {
            mj[jj + 0] = m_lds[bi][jj + 0];
            mj[jj + 1] = m_lds[bi][jj + 1];
            mj[jj + 2] = m_lds[bi][jj + 2];
            mj[jj + 3] = m_lds[bi][jj + 3];
            const int j0 = jt * JT + jj;
            const _Float16* c0 = w1h + (size_t)(((j0 + 0) << 6) + mj[jj + 0]) * D_MODEL + lane * 8;
            const _Float16* c1 = w1h + (size_t)(((j0 + 1) << 6) + mj[jj + 1]) * D_MODEL + lane * 8;
            const _Float16* c2 = w1h + (size_t)(((j0 + 2) << 6) + mj[jj + 2]) * D_MODEL + lane * 8;
            const _Float16* c3 = w1h + (size_t)(((j0 + 3) << 6) + mj[jj + 3]) * D_MODEL + lane * 8;
            const uint4 a0 = *(const uint4*)c0;
            const uint4 a1 = *(const uint4*)c1;
            const uint4 a2 = *(const uint4*)c2;
            const uint4 a3 = *(const uint4*)c3;
            const uint4 e0 = *(const uint4*)(c0 + 512);
            const uint4 e1 = *(const uint4*)(c1 + 512);
            const uint4 e2 = *(const uint4*)(c2 + 512);
            const uint4 e3 = *(const uint4*)(c3 + 512);

            float s0 = dot8(a0, xA, 0.f); s0 = dot8(e0, xB, s0);
            float s1 = dot8(a1, xA, 0.f); s1 = dot8(e1, xB, s1);
            float s2 = dot8(a2, xA, 0.f); s2 = dot8(e2, xB, s2);
            float s3 = dot8(a3, xA, 0.f); s3 = dot8(e3, xB, s3);

            s0 = wave_sum64(s0);
            s1 = wave_sum64(s1);
            s2 = wave_sum64(s2);
            s3 = wave_sum64(s3);
            rj[jj + 0] = fmaxf(bcast_lane(s0, WRITER_LANE), 0.f);
            rj[jj + 1] = fmaxf(bcast_lane(s1, WRITER_LANE), 0.f);
            rj[jj + 2] = fmaxf(bcast_lane(s2, WRITER_LANE), 0.f);
            rj[jj + 3] = fmaxf(bcast_lane(s3, WRITER_LANE), 0.f);
        }

        // phase 2 (no barrier): lane owns dims [lane*16, lane*16+16)
        float c0 = 0.f, c1 = 0.f, c2 = 0.f, c3 = 0.f;
        float c4 = 0.f, c5 = 0.f, c6 = 0.f, c7 = 0.f;
        float c8 = 0.f, c9 = 0.f, cA = 0.f, cB = 0.f;
        float cC = 0.f, cD = 0.f, cE = 0.f, cF = 0.f;
#pragma unroll
        for (int jj = 0; jj < JT; ++jj) {
            const float r = rj[jj];                    // SGPR scalar
            const _Float16* row = w2h
                + (size_t)(mj[jj] * D1 + jt * JT + jj) * D_MODEL + lane * 16;
            const uint4 v0 = *(const uint4*)row;
            const uint4 v1 = *(const uint4*)(row + 8);
            const h2 q0 = as_h2(v0.x), q1 = as_h2(v0.y);
            const h2 q2 = as_h2(v0.z), q3 = as_h2(v0.w);
            const h2 q4 = as_h2(v1.x), q5 = as_h2(v1.y);
            const h2 q6 = as_h2(v1.z), q7 = as_h2(v1.w);
            c0 = fmaf(r, (float)q0.x, c0); c1 = fmaf(r, (float)q0.y, c1);
            c2 = fmaf(r, (float)q1.x, c2); c3 = fmaf(r, (float)q1.y, c3);
            c4 = fmaf(r, (float)q2.x, c4); c5 = fmaf(r, (float)q2.y, c5);
            c6 = fmaf(r, (float)q3.x, c6); c7 = fmaf(r, (float)q3.y, c7);
            c8 = fmaf(r, (float)q4.x, c8); c9 = fmaf(r, (float)q4.y, c9);
            cA = fmaf(r, (float)q5.x, cA); cB = fmaf(r, (float)q5.y, cB);
            cC = fmaf(r, (float)q6.x, cC); cD = fmaf(r, (float)q6.y, cD);
            cE = fmaf(r, (float)q7.x, cE); cF = fmaf(r, (float)q7.y, cF);
        }
        u32x4 oA, oB;
        oA.x = pkh(c0, c1); oA.y = pkh(c2, c3);
        oA.z = pkh(c4, c5); oA.w = pkh(c6, c7);
        oB.x = pkh(c8, c9); oB.y = pkh(cA, cB);
        oB.z = pkh(cC, cD); oB.w = pkh(cE, cF);
        u16* pp = part + ((size_t)jt * BATCH + (b0 + bi)) * D_MODEL + lane * 16;
        __builtin_nontemporal_store(oA, (u32x4*)pp);
        __builtin_nontemporal_store(oB, (u32x4*)(pp + 8));
    }
}

// ---------------------------------------------------------------------------
// Reduce: res[b] = b2 + sum_jt part[jt][b] (f16 partials); mask echo chunk 0
// (r3-proven version, restored)
// ---------------------------------------------------------------------------
__global__ __launch_bounds__(256) void reduce_partials(const int* __restrict__ mask,
                                                       const float* __restrict__ b2,
                                                       const u16* __restrict__ part,
                                                       float* __restrict__ out) {
    const int b = blockIdx.x;
    const int t = threadIdx.x;
    if (t < D1) out[(size_t)b * D1 + t] = (float)mask[b * D1 + t];

    const int d0 = t * 4;
    const float4 bv = *(const float4*)(b2 + d0);
    float a0 = bv.x, a1 = bv.y, a2 = bv.z, a3 = bv.w;
#pragma unroll
    for (int jt = 0; jt < NJT; ++jt) {
        const uint2 v = *(const uint2*)(part + ((size_t)jt * BATCH + b) * D_MODEL + d0);
        const h2 p0 = as_h2(v.x), p1 = as_h2(v.y);
        a0 += (float)p0.x; a1 += (float)p0.y;
        a2 += (float)p1.x; a3 += (float)p1.y;
    }
    *(float4*)(out + (size_t)BATCH * D1 + (size_t)b * D_MODEL + d0) =
        make_float4(a0, a1, a2, a3);
}

// ---------------------------------------------------------------------------
// Fallback (tiny ws): fp32 path, raw strided w1 gather
// ---------------------------------------------------------------------------
__global__ __launch_bounds__(256) void sparse_ff_f32_raw(const int* __restrict__ mask,
                                                         const float* __restrict__ x,
                                                         const float* __restrict__ w1,
                                                         const float* __restrict__ w2,
                                                         const float* __restrict__ b2,
                                                         float* __restrict__ out) {
    __shared__ float x_lds[D_MODEL];
    __shared__ float relu_lds[D1];
    __shared__ int   m_lds[D1];
    const int b = blockIdx.x, t = threadIdx.x;
    const int wave = t >> 6, lane = t & 63;
    *(float4*)&x_lds[t * 4] = *(const float4*)(x + (size_t)b * D_MODEL + t * 4);
    if (t < D1) {
        const int mv = mask[b * D1 + t];
        m_lds[t] = mv;
        out[(size_t)b * D1 + t] = (float)mv;
    }
    __syncthreads();
    for (int jj = 0; jj < 32; ++jj) {
        const int j = wave * 32 + jj;
        const int m = m_lds[j];
        float acc = 0.f;
#pragma unroll
        for (int c = 0; c < 16; ++c) {
            const int d = c * 64 + lane;
            acc = fmaf(w1[(size_t)d * D_FF + j * N_ELEM + m], x_lds[d], acc);
        }
#pragma unroll
        for (int off = 32; off; off >>= 1) acc += __shfl_down(acc, off);
        if (lane == 0) relu_lds[j] = fmaxf(acc, 0.f);
    }
    __syncthreads();
    const int dm0 = t * 4;
    const float4 bv = *(const float4*)(b2 + dm0);
    float a0 = bv.x, a1 = bv.y, a2 = bv.z, a3 = bv.w;
    for (int j = 0; j < D1; ++j) {
        const float r = relu_lds[j];
        if (r > 0.f) {
            const float4 wv = *(const float4*)(w2 + (size_t)(m_lds[j] * D1 + j) * D_MODEL + dm0);
            a0 = fmaf(r, wv.x, a0); a1 = fmaf(r, wv.y, a1);
            a2 = fmaf(r, wv.z, a2); a3 = fmaf(r, wv.w, a3);
        }
    }
    *(float4*)(out + (size_t)BATCH * D1 + (size_t)b * D_MODEL + dm0) =
        make_float4(a0, a1, a2, a3);
}

extern "C" void kernel_launch(void* const* d_in, const int* in_sizes, int n_in,
                              void* d_out, int out_size, void* d_ws, size_t ws_size,
                              hipStream_t stream) {
    const int*   mask = (const int*)d_in[0];
    const float* x    = (const float*)d_in[1];
    const float* w1   = (const float*)d_in[2];
    const float* w2   = (const float*)d_in[3];
    const float* b2   = (const float*)d_in[4];
    float* out = (float*)d_out;

    const size_t w1h_bytes  = (size_t)D_FF * D_MODEL * sizeof(u16);          // 16 MiB
    const size_t w2h_bytes  = (size_t)D_FF * D_MODEL * sizeof(u16);          // 16 MiB
    const size_t part_bytes = (size_t)NJT * BATCH * D_MODEL * sizeof(u16);   // 32 MiB

    if (ws_size >= w1h_bytes + w2h_bytes + part_bytes) {
        u16* w1h  = (u16*)d_ws;
        u16* w2h  = (u16*)((char*)d_ws + w1h_bytes);
        u16* part = (u16*)((char*)d_ws + w1h_bytes + w2h_bytes);
        const int cast_blocks = (D_FF * D_MODEL / 8) / 256;                  // 4096
        prep_weights<<<TW1_BLOCKS + cast_blocks, 256, 0, stream>>>(w1, w1h, w2, w2h);
        sparse_ff_jt<<<(BATCH / B_T) * NJT, 256, 0, stream>>>(mask, x, w1h, w2h, part);
        reduce_partials<<<BATCH, 256, 0, stream>>>(mask, b2, part, out);
    } else {
        sparse_ff_f32_raw<<<BATCH, 256, 0, stream>>>(mask, x, w1, w2, b2, out);
    }
}

// Round 6
// 184.410 us; speedup vs baseline: 3.7457x; 1.0511x over previous
//
#include <hip/hip_runtime.h>

#define D_MODEL 1024
#define D_FF    8192
#define N_ELEM  64
#define D1      128
#define BATCH   2048
#define B_T     4      // batch rows per block (main kernel) -- r6: was 8
#define NJT     8      // j tiles (== XCD count)
#define JT      16     // j per tile

typedef unsigned short u16;
typedef unsigned int   u32;
typedef _Float16 h2    __attribute__((ext_vector_type(2)));
typedef float    f32x4 __attribute__((ext_vector_type(4)));
typedef u32      u32x2 __attribute__((ext_vector_type(2)));
typedef u32      u32x4 __attribute__((ext_vector_type(4)));

__device__ __forceinline__ h2 as_h2(u32 u) { union { u32 i; h2 h; } c; c.i = u; return c.h; }
__device__ __forceinline__ u32 pkh(float a, float b) {
    union { h2 h; u32 u; } c; c.h.x = (_Float16)a; c.h.y = (_Float16)b; return c.u;
}
__device__ __forceinline__ u16 f2h(float f) {
    union { _Float16 h; u16 u; } c; c.h = (_Float16)f; return c.u;
}
__device__ __forceinline__ f32x4 ntload4(const float* p) {
    return __builtin_nontemporal_load((const f32x4*)p);
}
// 2-way f16 dot with f32 accumulate: v_dot2_f32_f16 (2 MAC/inst).
__device__ __forceinline__ float dot2(u32 a, u32 b, float c) {
#if __has_builtin(__builtin_amdgcn_fdot2)
    return __builtin_amdgcn_fdot2(as_h2(a), as_h2(b), c, false);
#else
    const h2 ha = as_h2(a), hb = as_h2(b);
    c = fmaf((float)ha.x, (float)hb.x, c);
    return fmaf((float)ha.y, (float)hb.y, c);
#endif
}
__device__ __forceinline__ float dot8(uint4 w, uint4 q, float c) {
    c = dot2(w.x, q.x, c);
    c = dot2(w.y, q.y, c);
    c = dot2(w.z, q.z, c);
    c = dot2(w.w, q.w, c);
    return c;
}

// ---------------------------------------------------------------------------
// Wave-64 sum reduction on the VALU pipe via DPP (functionally verified in
// rounds 4 and 5). Total lands in lane 63.
// ---------------------------------------------------------------------------
#if __has_builtin(__builtin_amdgcn_update_dpp)
#define WRITER_LANE 63
#define DPP_ADD(x, ctrl)                                                      \
    x += __builtin_bit_cast(float, __builtin_amdgcn_update_dpp(               \
        0, __builtin_bit_cast(int, x), ctrl, 0xf, 0xf, true))
__device__ __forceinline__ float wave_sum64(float x) {
    DPP_ADD(x, 0x111);   // row_shr:1
    DPP_ADD(x, 0x112);   // row_shr:2
    DPP_ADD(x, 0x114);   // row_shr:4
    DPP_ADD(x, 0x118);   // row_shr:8  -> lane 15+16k holds row-k sum
    DPP_ADD(x, 0x142);   // row_bcast:15 -> lane31 = r0+r1, lane63 = r2+r3
    DPP_ADD(x, 0x143);   // row_bcast:31 -> lane63 = total
    return x;
}
#else
#define WRITER_LANE 0
__device__ __forceinline__ float wave_sum64(float x) {
#pragma unroll
    for (int off = 32; off; off >>= 1) x += __shfl_down(x, off);
    return x;
}
#endif

// ---------------------------------------------------------------------------
// Fused prep: blocks [0,2048) transpose+cast w1 -> w1h [j*64+e][d] f16;
// blocks [2048,6144) cast w2 -> f16. (Verified rounds 1-5.)
// ---------------------------------------------------------------------------
#define TW1_BLOCKS ((D_FF / 64) * (D_MODEL / 64))   // 2048
__global__ __launch_bounds__(256) void prep_weights(const float* __restrict__ w1,
                                                    u16* __restrict__ w1h,
                                                    const float* __restrict__ w2,
                                                    u16* __restrict__ w2h) {
    __shared__ float tile[64][65];
    if (blockIdx.x < TW1_BLOCKS) {
        const int c0 = (blockIdx.x & (D_FF / 64 - 1)) * 64;
        const int d0 = (blockIdx.x >> 7) * 64;          // D_FF/64 == 128
        const int tx = threadIdx.x & 15;
        const int ty = threadIdx.x >> 4;
#pragma unroll
        for (int r = 0; r < 4; ++r) {
            const int row = ty * 4 + r;
            const float4 v = *(const float4*)(w1 + (size_t)(d0 + row) * D_FF + c0 + tx * 4);
            tile[row][tx * 4 + 0] = v.x;
            tile[row][tx * 4 + 1] = v.y;
            tile[row][tx * 4 + 2] = v.z;
            tile[row][tx * 4 + 3] = v.w;
        }
        __syncthreads();
#pragma unroll
        for (int r = 0; r < 4; ++r) {
            const int c = ty * 4 + r;
            ushort4 o;
            o.x = f2h(tile[tx * 4 + 0][c]);
            o.y = f2h(tile[tx * 4 + 1][c]);
            o.z = f2h(tile[tx * 4 + 2][c]);
            o.w = f2h(tile[tx * 4 + 3][c]);
            *(ushort4*)(w1h + (size_t)(c0 + c) * D_MODEL + d0 + tx * 4) = o;
        }
    } else {
        const size_t i = ((size_t)(blockIdx.x - TW1_BLOCKS) * 256 + threadIdx.x) * 8;
        const float4 a = *(const float4*)(w2 + i);
        const float4 b = *(const float4*)(w2 + i + 4);
        ushort4 oa, ob;
        oa.x = f2h(a.x); oa.y = f2h(a.y); oa.z = f2h(a.z); oa.w = f2h(a.w);
        ob.x = f2h(b.x); ob.y = f2h(b.y); ob.z = f2h(b.z); ob.w = f2h(b.w);
        *(ushort4*)(w2h + i)     = oa;
        *(ushort4*)(w2h + i + 4) = ob;
    }
}

// ---------------------------------------------------------------------------
// Main, round 6: exact r3 inner structure (62us best) with B_T=4 -> 4096
// blocks. Rationale: r3 pinned at 62us with occupancy only 70% and ~8
// blocks/CU exactly matching the grid -- ramp/tail leaves CUs partially
// drained ~30% of the time. 16 queued blocks/CU + 8.7KB LDS deepens
// residency and halves the per-block serial chain. DPP reduce retained
// (verified r4/r5; VALU pipe instead of ds_bpermute).
//   phase 1: wave owns 1 bi; 4 j per step, 4 independent dot+reduce chains.
//   phase 2: branchless, wave-pair split, 8 dims/thread, paired jj streams.
// ---------------------------------------------------------------------------
__global__ __launch_bounds__(256) void sparse_ff_jt(const int* __restrict__ mask,
                                                    const float* __restrict__ x,
                                                    const u16* __restrict__ w1h_,
                                                    const u16* __restrict__ w2h_,
                                                    u16* __restrict__ part) {
    const _Float16* w1h = (const _Float16*)w1h_;
    const _Float16* w2h = (const _Float16*)w2h_;
    __shared__ u16   x_lds[B_T][D_MODEL];   // f16, 8 KB
    __shared__ float r_lds[B_T][JT];
    __shared__ int   m_lds[B_T][JT];

    const int jt = blockIdx.x & (NJT - 1);          // XCD-affine j tile
    const int b0 = (blockIdx.x >> 3) * B_T;
    const int t = threadIdx.x;
    const int wave = t >> 6;
    const int lane = t & 63;

    // stage x rows (f32 nt coalesced -> f16 LDS) + mask rows, one barrier
#pragma unroll
    for (int r = 0; r < B_T; ++r) {
        const f32x4 v = ntload4(x + (size_t)(b0 + r) * D_MODEL + t * 4);
        u32x2 o; o.x = pkh(v.x, v.y); o.y = pkh(v.z, v.w);
        *(u32x2*)&x_lds[r][t * 4] = o;
    }
    if (t < B_T * JT) {
        m_lds[t >> 4][t & 15] = mask[(b0 + (t >> 4)) * D1 + jt * JT + (t & 15)];
    }
    __syncthreads();

    // ---- phase 1: wave owns bi == wave; 16 j, 4 j per step ----
    {
        const int bi = wave;
        const uint4 xA = *(const uint4*)&x_lds[bi][lane * 8];        // dims lane*8..+8
        const uint4 xB = *(const uint4*)&x_lds[bi][512 + lane * 8];  // dims 512+..

#pragma unroll
        for (int jj = 0; jj < JT; jj += 4) {
            const int j0 = jt * JT + jj;
            const _Float16* c0 = w1h + (size_t)(((j0 + 0) << 6) + m_lds[bi][jj + 0]) * D_MODEL + lane * 8;
            const _Float16* c1 = w1h + (size_t)(((j0 + 1) << 6) + m_lds[bi][jj + 1]) * D_MODEL + lane * 8;
            const _Float16* c2 = w1h + (size_t)(((j0 + 2) << 6) + m_lds[bi][jj + 2]) * D_MODEL + lane * 8;
            const _Float16* c3 = w1h + (size_t)(((j0 + 3) << 6) + m_lds[bi][jj + 3]) * D_MODEL + lane * 8;
            const uint4 a0 = *(const uint4*)c0;
            const uint4 a1 = *(const uint4*)c1;
            const uint4 a2 = *(const uint4*)c2;
            const uint4 a3 = *(const uint4*)c3;
            const uint4 e0 = *(const uint4*)(c0 + 512);
            const uint4 e1 = *(const uint4*)(c1 + 512);
            const uint4 e2 = *(const uint4*)(c2 + 512);
            const uint4 e3 = *(const uint4*)(c3 + 512);

            float s0 = dot8(a0, xA, 0.f); s0 = dot8(e0, xB, s0);
            float s1 = dot8(a1, xA, 0.f); s1 = dot8(e1, xB, s1);
            float s2 = dot8(a2, xA, 0.f); s2 = dot8(e2, xB, s2);
            float s3 = dot8(a3, xA, 0.f); s3 = dot8(e3, xB, s3);

            s0 = wave_sum64(s0);
            s1 = wave_sum64(s1);
            s2 = wave_sum64(s2);
            s3 = wave_sum64(s3);
            if (lane == WRITER_LANE) {
                r_lds[bi][jj + 0] = fmaxf(s0, 0.f);
                r_lds[bi][jj + 1] = fmaxf(s1, 0.f);
                r_lds[bi][jj + 2] = fmaxf(s2, 0.f);
                r_lds[bi][jj + 3] = fmaxf(s3, 0.f);
            }
        }
    }
    __syncthreads();

    // ---- phase 2: branchless, wave-pair split, 8 dims/thread, paired jj ----
    const int halfsel = t >> 7;            // waves 0-1 -> bi even, 2-3 -> bi odd
    const int d0q = (t & 127) * 8;
#pragma unroll
    for (int p = 0; p < B_T / 2; ++p) {
        const int bi = p * 2 + halfsel;
        float e0 = 0.f, e1 = 0.f, e2 = 0.f, e3 = 0.f;
        float e4 = 0.f, e5 = 0.f, e6 = 0.f, e7 = 0.f;
        float o0 = 0.f, o1 = 0.f, o2 = 0.f, o3 = 0.f;
        float o4 = 0.f, o5 = 0.f, o6 = 0.f, o7 = 0.f;
#pragma unroll
        for (int jj = 0; jj < JT; jj += 2) {
            const float rE = r_lds[bi][jj];
            const float rO = r_lds[bi][jj + 1];
            const _Float16* rowE = w2h
                + (size_t)(m_lds[bi][jj] * D1 + jt * JT + jj) * D_MODEL + d0q;
            const _Float16* rowO = w2h
                + (size_t)(m_lds[bi][jj + 1] * D1 + jt * JT + jj + 1) * D_MODEL + d0q;
            const uint4 vE = *(const uint4*)rowE;
            const uint4 vO = *(const uint4*)rowO;
            {
                const h2 q0 = as_h2(vE.x), q1 = as_h2(vE.y);
                const h2 q2 = as_h2(vE.z), q3 = as_h2(vE.w);
                e0 = fmaf(rE, (float)q0.x, e0); e1 = fmaf(rE, (float)q0.y, e1);
                e2 = fmaf(rE, (float)q1.x, e2); e3 = fmaf(rE, (float)q1.y, e3);
                e4 = fmaf(rE, (float)q2.x, e4); e5 = fmaf(rE, (float)q2.y, e5);
                e6 = fmaf(rE, (float)q3.x, e6); e7 = fmaf(rE, (float)q3.y, e7);
            }
            {
                const h2 q0 = as_h2(vO.x), q1 = as_h2(vO.y);
                const h2 q2 = as_h2(vO.z), q3 = as_h2(vO.w);
                o0 = fmaf(rO, (float)q0.x, o0); o1 = fmaf(rO, (float)q0.y, o1);
                o2 = fmaf(rO, (float)q1.x, o2); o3 = fmaf(rO, (float)q1.y, o3);
                o4 = fmaf(rO, (float)q2.x, o4); o5 = fmaf(rO, (float)q2.y, o5);
                o6 = fmaf(rO, (float)q3.x, o6); o7 = fmaf(rO, (float)q3.y, o7);
            }
        }
        u32x4 o;
        o.x = pkh(e0 + o0, e1 + o1); o.y = pkh(e2 + o2, e3 + o3);
        o.z = pkh(e4 + o4, e5 + o5); o.w = pkh(e6 + o6, e7 + o7);
        u16* pp = part + ((size_t)jt * BATCH + (b0 + bi)) * D_MODEL + d0q;
        __builtin_nontemporal_store(o, (u32x4*)pp);
    }
}

// ---------------------------------------------------------------------------
// Reduce: res[b] = b2 + sum_jt part[jt][b] (f16 partials); mask echo chunk 0
// ---------------------------------------------------------------------------
__global__ __launch_bounds__(256) void reduce_partials(const int* __restrict__ mask,
                                                       const float* __restrict__ b2,
                                                       const u16* __restrict__ part,
                                                       float* __restrict__ out) {
    const int b = blockIdx.x;
    const int t = threadIdx.x;
    if (t < D1) out[(size_t)b * D1 + t] = (float)mask[b * D1 + t];

    const int d0 = t * 4;
    const float4 bv = *(const float4*)(b2 + d0);
    float a0 = bv.x, a1 = bv.y, a2 = bv.z, a3 = bv.w;
#pragma unroll
    for (int jt = 0; jt < NJT; ++jt) {
        const uint2 v = *(const uint2*)(part + ((size_t)jt * BATCH + b) * D_MODEL + d0);
        const h2 p0 = as_h2(v.x), p1 = as_h2(v.y);
        a0 += (float)p0.x; a1 += (float)p0.y;
        a2 += (float)p1.x; a3 += (float)p1.y;
    }
    *(float4*)(out + (size_t)BATCH * D1 + (size_t)b * D_MODEL + d0) =
        make_float4(a0, a1, a2, a3);
}

// ---------------------------------------------------------------------------
// Fallback (tiny ws): fp32 path, raw strided w1 gather
// ---------------------------------------------------------------------------
__global__ __launch_bounds__(256) void sparse_ff_f32_raw(const int* __restrict__ mask,
                                                         const float* __restrict__ x,
                                                         const float* __restrict__ w1,
                                                         const float* __restrict__ w2,
                                                         const float* __restrict__ b2,
                                                         float* __restrict__ out) {
    __shared__ float x_lds[D_MODEL];
    __shared__ float relu_lds[D1];
    __shared__ int   m_lds[D1];
    const int b = blockIdx.x, t = threadIdx.x;
    const int wave = t >> 6, lane = t & 63;
    *(float4*)&x_lds[t * 4] = *(const float4*)(x + (size_t)b * D_MODEL + t * 4);
    if (t < D1) {
        const int mv = mask[b * D1 + t];
        m_lds[t] = mv;
        out[(size_t)b * D1 + t] = (float)mv;
    }
    __syncthreads();
    for (int jj = 0; jj < 32; ++jj) {
        const int j = wave * 32 + jj;
        const int m = m_lds[j];
        float acc = 0.f;
#pragma unroll
        for (int c = 0; c < 16; ++c) {
            const int d = c * 64 + lane;
            acc = fmaf(w1[(size_t)d * D_FF + j * N_ELEM + m], x_lds[d], acc);
        }
#pragma unroll
        for (int off = 32; off; off >>= 1) acc += __shfl_down(acc, off);
        if (lane == 0) relu_lds[j] = fmaxf(acc, 0.f);
    }
    __syncthreads();
    const int dm0 = t * 4;
    const float4 bv = *(const float4*)(b2 + dm0);
    float a0 = bv.x, a1 = bv.y, a2 = bv.z, a3 = bv.w;
    for (int j = 0; j < D1; ++j) {
        const float r = relu_lds[j];
        if (r > 0.f) {
            const float4 wv = *(const float4*)(w2 + (size_t)(m_lds[j] * D1 + j) * D_MODEL + dm0);
            a0 = fmaf(r, wv.x, a0); a1 = fmaf(r, wv.y, a1);
            a2 = fmaf(r, wv.z, a2); a3 = fmaf(r, wv.w, a3);
        }
    }
    *(float4*)(out + (size_t)BATCH * D1 + (size_t)b * D_MODEL + dm0) =
        make_float4(a0, a1, a2, a3);
}

extern "C" void kernel_launch(void* const* d_in, const int* in_sizes, int n_in,
                              void* d_out, int out_size, void* d_ws, size_t ws_size,
                              hipStream_t stream) {
    const int*   mask = (const int*)d_in[0];
    const float* x    = (const float*)d_in[1];
    const float* w1   = (const float*)d_in[2];
    const float* w2   = (const float*)d_in[3];
    const float* b2   = (const float*)d_in[4];
    float* out = (float*)d_out;

    const size_t w1h_bytes  = (size_t)D_FF * D_MODEL * sizeof(u16);          // 16 MiB
    const size_t w2h_bytes  = (size_t)D_FF * D_MODEL * sizeof(u16);          // 16 MiB
    const size_t part_bytes = (size_t)NJT * BATCH * D_MODEL * sizeof(u16);   // 32 MiB

    if (ws_size >= w1h_bytes + w2h_bytes + part_bytes) {
        u16* w1h  = (u16*)d_ws;
        u16* w2h  = (u16*)((char*)d_ws + w1h_bytes);
        u16* part = (u16*)((char*)d_ws + w1h_bytes + w2h_bytes);
        const int cast_blocks = (D_FF * D_MODEL / 8) / 256;                  // 4096
        prep_weights<<<TW1_BLOCKS + cast_blocks, 256, 0, stream>>>(w1, w1h, w2, w2h);
        sparse_ff_jt<<<(BATCH / B_T) * NJT, 256, 0, stream>>>(mask, x, w1h, w2h, part);
        reduce_partials<<<BATCH, 256, 0, stream>>>(mask, b2, part, out);
    } else {
        sparse_ff_f32_raw<<<BATCH, 256, 0, stream>>>(mask, x, w1, w2, b2, out);
    }
}